// Round 1
// baseline (757.155 us; speedup 1.0000x reference)
//
#include <hip/hip_runtime.h>

// EntityAwareAttention on MI355X (gfx950), bf16 MFMA pipeline.
// Stages: (1) W fp32->bf16, (2) key-bias KB[b][s], (3) GEMM Q,K [s][h] bf16,
// (4) GEMM V^T [d][s] bf16, (5) single-pass flash attention (online softmax).
// Workspace use: ~75.5 MB.

typedef short bf16x8 __attribute__((ext_vector_type(8)));
typedef float f32x4 __attribute__((ext_vector_type(4)));

#define MFMA16(a, b, c) __builtin_amdgcn_mfma_f32_16x16x32_bf16(a, b, c, 0, 0, 0)

__device__ __forceinline__ unsigned short f2bf(float f) {
  unsigned u = __float_as_uint(f);
  u = u + 0x7FFFu + ((u >> 16) & 1u);  // RNE
  return (unsigned short)(u >> 16);
}

__device__ __forceinline__ void gll16(const void* g, void* l) {
  __builtin_amdgcn_global_load_lds(
      (const __attribute__((address_space(1))) unsigned int*)g,
      (__attribute__((address_space(3))) unsigned int*)l, 16, 0, 0);
}

#define SCALE_INV 0.03608439182435161f  // 1/sqrt(768)

// ---------------- weight conversion ----------------
__global__ void convert_w_kernel(const float* __restrict__ w0, const float* __restrict__ w1,
                                 const float* __restrict__ w2, unsigned short* __restrict__ o0,
                                 unsigned short* __restrict__ o1, unsigned short* __restrict__ o2) {
  const int which = blockIdx.y;
  const float* s = which == 0 ? w0 : (which == 1 ? w1 : w2);
  unsigned short* d = which == 0 ? o0 : (which == 1 ? o1 : o2);
  const int i = (blockIdx.x * 256 + threadIdx.x) * 4;  // 589824 elems per matrix
  float4 v = *(const float4*)(s + i);
  ushort4 r = make_ushort4(f2bf(v.x), f2bf(v.y), f2bf(v.z), f2bf(v.w));
  *(ushort4*)(d + i) = r;
}

// ---------------- key bias ----------------
__global__ void kb_init_kernel(const float* __restrict__ mask, float* __restrict__ kb) {
  const int i = blockIdx.x * 256 + threadIdx.x;  // 16384
  kb[i] = (1.0f - mask[i]) * -10000.0f;
}

__global__ void kb_scatter_kernel(const int* __restrict__ ep, float* __restrict__ kb) {
  const int t = threadIdx.x;  // 256 = 4 batches * 64 entities
  const int b = t >> 6, e = t & 63;
  const int pos = ep[b * 64 + e];
  atomicAdd(kb + b * 4096 + pos, 1.0f);
}

// ---------------- GEMM: Q and K = hs @ W^T + bias, bf16 out [m][o] ----------------
// A = hs fp32 [16384 x 768] (manual cvt staging), B = W bf16 [768(o) x 768(h)] (global_load_lds)
__global__ __launch_bounds__(256, 3) void gemm_qk_kernel(
    const float* __restrict__ hs, const unsigned short* __restrict__ Wqb,
    const unsigned short* __restrict__ Wkb, const float* __restrict__ bq,
    const float* __restrict__ bk, unsigned short* __restrict__ Qb,
    unsigned short* __restrict__ Kb) {
  const int z = blockIdx.z;
  const unsigned short* W = z ? Wkb : Wqb;
  const float* bias = z ? bk : bq;
  unsigned short* out = z ? Kb : Qb;
  const int m0 = blockIdx.x * 128;
  const int n0 = blockIdx.y * 128;

  __shared__ __align__(16) unsigned short Ab[2][128 * 32];
  __shared__ __align__(16) unsigned short Bb[2][128 * 32];

  const int t = threadIdx.x;
  const int lane = t & 63;
  const int w = t >> 6;
  const int wm = w & 1, wn = w >> 1;

  f32x4 acc[4][4] = {};
  float4 areg[4];

  auto loadA = [&](int kk) {
#pragma unroll
    for (int r = 0; r < 4; r++) {
      int u = r * 256 + t;
      int row = u >> 3, g = u & 7;
      areg[r] = *(const float4*)(hs + (size_t)(m0 + row) * 768 + kk + g * 4);
    }
  };
  auto writeA = [&](int buf) {
#pragma unroll
    for (int r = 0; r < 4; r++) {
      int u = r * 256 + t;
      int row = u >> 3, g = u & 7;
      int cc = (g >> 1) ^ ((row >> 1) & 3);
      ushort4 v = make_ushort4(f2bf(areg[r].x), f2bf(areg[r].y), f2bf(areg[r].z), f2bf(areg[r].w));
      *(ushort4*)(&Ab[buf][row * 32 + cc * 8 + (g & 1) * 4]) = v;
    }
  };
  auto issueB = [&](int kk, int buf) {
#pragma unroll
    for (int r = 0; r < 2; r++) {
      int u = r * 256 + t;
      int o = u >> 2, cc = u & 3;
      int c = cc ^ ((o >> 1) & 3);
      gll16(W + (size_t)(n0 + o) * 768 + kk + c * 8, &Bb[buf][u * 8]);
    }
  };

  loadA(0);
  issueB(0, 0);
  writeA(0);
  loadA(32);
  __syncthreads();

  for (int k = 0; k < 24; k++) {
    const int buf = k & 1;
    if (k < 23) issueB((k + 1) * 32, buf ^ 1);
    bf16x8 af[4], bfr[4];
#pragma unroll
    for (int mt = 0; mt < 4; mt++) {
      int row = wm * 64 + mt * 16 + (lane & 15);
      int cc = (lane >> 4) ^ ((row >> 1) & 3);
      af[mt] = *(const bf16x8*)(&Ab[buf][row * 32 + cc * 8]);
    }
#pragma unroll
    for (int nt = 0; nt < 4; nt++) {
      int row = wn * 64 + nt * 16 + (lane & 15);
      int cc = (lane >> 4) ^ ((row >> 1) & 3);
      bfr[nt] = *(const bf16x8*)(&Bb[buf][row * 32 + cc * 8]);
    }
#pragma unroll
    for (int mt = 0; mt < 4; mt++)
#pragma unroll
      for (int nt = 0; nt < 4; nt++) acc[mt][nt] = MFMA16(af[mt], bfr[nt], acc[mt][nt]);
    if (k < 23) {
      writeA(buf ^ 1);
      if (k < 22) loadA((k + 2) * 32);
    }
    __syncthreads();
  }

#pragma unroll
  for (int nt = 0; nt < 4; nt++) {
    int col = n0 + wn * 64 + nt * 16 + (lane & 15);
    float bv = bias[col];
#pragma unroll
    for (int mt = 0; mt < 4; mt++) {
#pragma unroll
      for (int i = 0; i < 4; i++) {
        int row = m0 + wm * 64 + mt * 16 + (lane >> 4) * 4 + i;
        out[(size_t)row * 768 + col] = f2bf(acc[mt][nt][i] + bv);
      }
    }
  }
}

// ---------------- GEMM: V^T[b][o][s] = W_v @ hs^T + bv ----------------
// A = Wv bf16 [768(o) x 768(h)] (global_load_lds), B = hs fp32 (manual cvt staging)
__global__ __launch_bounds__(256, 3) void gemm_vt_kernel(const float* __restrict__ hs,
                                                         const unsigned short* __restrict__ Wvb,
                                                         const float* __restrict__ bv,
                                                         unsigned short* __restrict__ Vt) {
  const int m0 = blockIdx.x * 128;  // o
  const int n0 = blockIdx.y * 128;  // m = b*4096+s

  __shared__ __align__(16) unsigned short Ab[2][128 * 32];
  __shared__ __align__(16) unsigned short Bb[2][128 * 32];

  const int t = threadIdx.x;
  const int lane = t & 63;
  const int w = t >> 6;
  const int wm = w & 1, wn = w >> 1;

  f32x4 acc[4][4] = {};
  float4 breg[4];

  auto loadB = [&](int kk) {
#pragma unroll
    for (int r = 0; r < 4; r++) {
      int u = r * 256 + t;
      int row = u >> 3, g = u & 7;
      breg[r] = *(const float4*)(hs + (size_t)(n0 + row) * 768 + kk + g * 4);
    }
  };
  auto writeB = [&](int buf) {
#pragma unroll
    for (int r = 0; r < 4; r++) {
      int u = r * 256 + t;
      int row = u >> 3, g = u & 7;
      int cc = (g >> 1) ^ ((row >> 1) & 3);
      ushort4 v = make_ushort4(f2bf(breg[r].x), f2bf(breg[r].y), f2bf(breg[r].z), f2bf(breg[r].w));
      *(ushort4*)(&Bb[buf][row * 32 + cc * 8 + (g & 1) * 4]) = v;
    }
  };
  auto issueA = [&](int kk, int buf) {
#pragma unroll
    for (int r = 0; r < 2; r++) {
      int u = r * 256 + t;
      int o = u >> 2, cc = u & 3;
      int c = cc ^ ((o >> 1) & 3);
      gll16(Wvb + (size_t)(m0 + o) * 768 + kk + c * 8, &Ab[buf][u * 8]);
    }
  };

  loadB(0);
  issueA(0, 0);
  writeB(0);
  loadB(32);
  __syncthreads();

  for (int k = 0; k < 24; k++) {
    const int buf = k & 1;
    if (k < 23) issueA((k + 1) * 32, buf ^ 1);
    bf16x8 af[4], bfr[4];
#pragma unroll
    for (int mt = 0; mt < 4; mt++) {
      int row = wm * 64 + mt * 16 + (lane & 15);
      int cc = (lane >> 4) ^ ((row >> 1) & 3);
      af[mt] = *(const bf16x8*)(&Ab[buf][row * 32 + cc * 8]);
    }
#pragma unroll
    for (int nt = 0; nt < 4; nt++) {
      int row = wn * 64 + nt * 16 + (lane & 15);
      int cc = (lane >> 4) ^ ((row >> 1) & 3);
      bfr[nt] = *(const bf16x8*)(&Bb[buf][row * 32 + cc * 8]);
    }
#pragma unroll
    for (int mt = 0; mt < 4; mt++)
#pragma unroll
      for (int nt = 0; nt < 4; nt++) acc[mt][nt] = MFMA16(af[mt], bfr[nt], acc[mt][nt]);
    if (k < 23) {
      writeB(buf ^ 1);
      if (k < 22) loadB((k + 2) * 32);
    }
    __syncthreads();
  }

#pragma unroll
  for (int mt = 0; mt < 4; mt++) {
#pragma unroll
    for (int i = 0; i < 4; i++) {
      int row_o = m0 + wm * 64 + mt * 16 + (lane >> 4) * 4 + i;
      float bb = bv[row_o];
#pragma unroll
      for (int nt = 0; nt < 4; nt++) {
        int mcol = n0 + wn * 64 + nt * 16 + (lane & 15);
        int bat = mcol >> 12, s = mcol & 4095;
        Vt[(size_t)bat * 768 * 4096 + (size_t)row_o * 4096 + s] = f2bf(acc[mt][nt][i] + bb);
      }
    }
  }
}

// ---------------- flash attention ----------------
// 8 waves: mg = w&3 (16 q-rows each), hg = w>>2 (QK: contraction half; PV: d-slice half).
// BM=64 queries/block, BN=32 keys/iter, 128 iters. LDS ~157KB -> 1 block/CU.
__global__ __launch_bounds__(512, 2) void flash_kernel(const unsigned short* __restrict__ Qb,
                                                       const unsigned short* __restrict__ Kb,
                                                       const unsigned short* __restrict__ Vt,
                                                       const float* __restrict__ KB,
                                                       float* __restrict__ out) {
  __shared__ __align__(16) unsigned short kbuf[2][32 * 768];  // 96 KB
  __shared__ __align__(16) unsigned short vbuf[768 * 32];     // 48 KB
  __shared__ __align__(16) unsigned short pbuf[64 * 32];      // 4 KB
  __shared__ float sx[64 * 32];                               // 8 KB  (hg=1 partial S)
  __shared__ float st_m[64], st_l[64], st_a[64];

  const int t = threadIdx.x;
  const int lane = t & 63;
  const int w = t >> 6;
  const int mg = w & 3, hg = w >> 2;
  const int flat = blockIdx.x;  // batch-major swizzle: XCD k serves batch k&3
  const int b = flat & 3, qt = flat >> 2;
  const int q0 = qt * 64;

  const unsigned short* Qg = Qb + (size_t)b * 4096 * 768;
  const unsigned short* Kg = Kb + (size_t)b * 4096 * 768;
  const unsigned short* Vg = Vt + (size_t)b * 768 * 4096;
  const float* KBb = KB + b * 4096;

  bf16x8 qf[12];  // this wave's Q rows, its contraction half, resident in regs
  {
    const unsigned short* qp =
        Qg + (size_t)(q0 + mg * 16 + (lane & 15)) * 768 + hg * 384 + (lane >> 4) * 8;
#pragma unroll
    for (int i = 0; i < 12; i++) qf[i] = *(const bf16x8*)(qp + i * 32);
  }
  if (t < 64) {
    st_m[t] = -1e30f;
    st_l[t] = 0.0f;
  }

  f32x4 oacc[24] = {};  // 16 rows x 384 d per wave

  auto stageK = [&](int j, int buf) {
#pragma unroll
    for (int r = 0; r < 6; r++) {
      int u = r * 512 + t;
      int ks = u >> 7;
      int rem = u & 127;
      int key = rem >> 2, cc = rem & 3;
      int c = cc ^ ((key >> 1) & 3);
      gll16(Kg + (size_t)(j * 32 + key) * 768 + ks * 32 + c * 8, &kbuf[buf][u * 8]);
    }
  };
  auto stageV = [&](int j) {
#pragma unroll
    for (int r = 0; r < 6; r++) {
      int u = r * 512 + t;
      int d = u >> 2, cc = u & 3;
      int c = cc ^ ((d >> 1) & 3);
      gll16(Vg + (size_t)d * 4096 + j * 32 + c * 8, &vbuf[u * 8]);
    }
  };

  stageK(0, 0);

  for (int j = 0; j < 128; j++) {
    __syncthreads();  // (A) prior PV reads done
    stageV(j);
    if (j < 127) stageK(j + 1, (j + 1) & 1);
    float kb0 = 0.f, kb1 = 0.f;
    if (hg == 0) {
      kb0 = KBb[j * 32 + (lane & 15)];
      kb1 = KBb[j * 32 + 16 + (lane & 15)];
    }
    // QK partial (this wave's contraction half), both 16-col subtiles
    f32x4 s0 = {}, s1 = {};
    const unsigned short* kl = kbuf[j & 1];
#pragma unroll
    for (int kt = 0; kt < 12; kt++) {
      int tt = hg * 12 + kt;
      int key0 = lane & 15;
      int cc0 = (lane >> 4) ^ ((key0 >> 1) & 3);
      bf16x8 b0 = *(const bf16x8*)(kl + (tt * 128 + key0 * 4 + cc0) * 8);
      int key1 = 16 + key0;
      int cc1 = (lane >> 4) ^ ((key1 >> 1) & 3);
      bf16x8 b1 = *(const bf16x8*)(kl + (tt * 128 + key1 * 4 + cc1) * 8);
      s0 = MFMA16(qf[kt], b0, s0);
      s1 = MFMA16(qf[kt], b1, s1);
    }
    if (hg == 1) {
      int col = lane & 15;
#pragma unroll
      for (int i = 0; i < 4; i++) {
        int row = mg * 16 + (lane >> 4) * 4 + i;
        sx[row * 32 + col] = s0[i];
        sx[row * 32 + 16 + col] = s1[i];
      }
    }
    __syncthreads();  // (B) partials visible
    if (hg == 0) {
      int col = lane & 15;
#pragma unroll
      for (int i = 0; i < 4; i++) {
        int row = mg * 16 + (lane >> 4) * 4 + i;
        float v0 = (s0[i] + sx[row * 32 + col]) * SCALE_INV + kb0;
        float v1 = (s1[i] + sx[row * 32 + 16 + col]) * SCALE_INV + kb1;
        float mx = fmaxf(v0, v1);
#pragma unroll
        for (int d2 = 1; d2 < 16; d2 <<= 1) mx = fmaxf(mx, __shfl_xor(mx, d2, 16));
        float mold = st_m[row];
        float mn = fmaxf(mold, mx);
        float e0 = __expf(v0 - mn);
        float e1 = __expf(v1 - mn);
        float rs = e0 + e1;
#pragma unroll
        for (int d2 = 1; d2 < 16; d2 <<= 1) rs += __shfl_xor(rs, d2, 16);
        if (col == 0) {
          float al = __expf(mold - mn);
          st_m[row] = mn;
          st_a[row] = al;
          st_l[row] = st_l[row] * al + rs;
        }
        int rsw = (row >> 1) & 3;
        int c0 = (col >> 3) ^ rsw;
        pbuf[row * 32 + c0 * 8 + (col & 7)] = f2bf(e0);
        int c1 = ((col + 16) >> 3) ^ rsw;
        pbuf[row * 32 + c1 * 8 + (col & 7)] = f2bf(e1);
      }
    }
    __syncthreads();  // (C) P + V + alpha ready
    {
      int rb = mg * 16 + (lane >> 4) * 4;
      float al0 = st_a[rb], al1 = st_a[rb + 1], al2 = st_a[rb + 2], al3 = st_a[rb + 3];
      int pm = mg * 16 + (lane & 15);
      int ccp = (lane >> 4) ^ ((pm >> 1) & 3);
      bf16x8 pf = *(const bf16x8*)(pbuf + (pm * 4 + ccp) * 8);
#pragma unroll
      for (int nt = 0; nt < 24; nt++) {
        oacc[nt][0] *= al0;
        oacc[nt][1] *= al1;
        oacc[nt][2] *= al2;
        oacc[nt][3] *= al3;
        int d = hg * 384 + nt * 16 + (lane & 15);
        int cc = (lane >> 4) ^ ((d >> 1) & 3);
        bf16x8 vf = *(const bf16x8*)(vbuf + (d * 4 + cc) * 8);
        oacc[nt] = MFMA16(pf, vf, oacc[nt]);
      }
    }
  }
  __syncthreads();
  {
    int rb = mg * 16 + (lane >> 4) * 4;
    float l0 = 1.0f / st_l[rb], l1 = 1.0f / st_l[rb + 1];
    float l2 = 1.0f / st_l[rb + 2], l3 = 1.0f / st_l[rb + 3];
#pragma unroll
    for (int nt = 0; nt < 24; nt++) {
      int d = hg * 384 + nt * 16 + (lane & 15);
      size_t base = ((size_t)(b * 4096 + q0 + rb)) * 768 + d;
      out[base] = oacc[nt][0] * l0;
      out[base + 768] = oacc[nt][1] * l1;
      out[base + 2 * 768] = oacc[nt][2] * l2;
      out[base + 3 * 768] = oacc[nt][3] * l3;
    }
  }
}

extern "C" void kernel_launch(void* const* d_in, const int* in_sizes, int n_in, void* d_out,
                              int out_size, void* d_ws, size_t ws_size, hipStream_t stream) {
  const float* hs = (const float*)d_in[0];
  const float* mask = (const float*)d_in[1];
  const int* ep = (const int*)d_in[2];
  const float* Wq = (const float*)d_in[3];
  const float* bq = (const float*)d_in[4];
  const float* Wk = (const float*)d_in[5];
  const float* bk = (const float*)d_in[6];
  const float* Wv = (const float*)d_in[7];
  const float* bv = (const float*)d_in[8];
  float* outp = (float*)d_out;

  char* ws = (char*)d_ws;
  unsigned short* Qb = (unsigned short*)(ws);                  // 25165824 B
  unsigned short* Kb = (unsigned short*)(ws + 25165824);       // 25165824 B
  unsigned short* Vt = (unsigned short*)(ws + 50331648);       // 25165824 B
  unsigned short* Wqb = (unsigned short*)(ws + 75497472);      // 1179648 B
  unsigned short* Wkb = (unsigned short*)(ws + 76677120);      // 1179648 B
  unsigned short* Wvb = (unsigned short*)(ws + 77856768);      // 1179648 B
  float* KBp = (float*)(ws + 79036416);                        // 65536 B

  convert_w_kernel<<<dim3(576, 3), 256, 0, stream>>>(Wq, Wk, Wv, Wqb, Wkb, Wvb);
  kb_init_kernel<<<64, 256, 0, stream>>>(mask, KBp);
  kb_scatter_kernel<<<1, 256, 0, stream>>>(ep, KBp);
  gemm_qk_kernel<<<dim3(128, 6, 2), 256, 0, stream>>>(hs, Wqb, Wkb, bq, bk, Qb, Kb);
  gemm_vt_kernel<<<dim3(6, 128), 256, 0, stream>>>(hs, Wvb, bv, Vt);
  flash_kernel<<<256, 512, 0, stream>>>(Qb, Kb, Vt, KBp, outp);
}